// Round 8
// baseline (282.358 us; speedup 1.0000x reference)
//
#include <hip/hip_runtime.h>
#include <cmath>

// ---------------------------------------------------------------------------
// 3-layer GCN, atomic-free aggregate, bf16 data path, MFMA epilogue.
// CSR build (R8, 4 dispatches, no memset):
//   bhist_cvt_k : per-4096-edge-segment LDS hist -> part[seg][bkt] (plain
//                 stores, no init needed) + grid-stride x->bf16 convert
//   bscan_k     : 1 block: sum part over segs, scan 391 buckets -> bbase/bcur
//   bucket_k    : scatter (src,dst) -> per-bucket regions of ebuf (single-
//                 block-owned lines; R5 showed random 4B stores cost 64B each)
//   fillb_k     : per bucket: LDS 256-node hist + block scan -> row_off
//                 (coalesced) + scatter src -> block-private ssrc region
// Fused layer: stage tile's edge indices into LDS, 16 row-loads in flight
// per node (R7 had 8; Poisson(8) degrees -> 1.45 rounds/node, now 1.03),
// fp32 accumulate -> bf16 rows in LDS -> mfma_f32_16x16x32_bf16 -> bias
// (+relu->bf16 | +log_softmax->fp32).
// ---------------------------------------------------------------------------

#define B1_EPB 4096      // edges per histogram/bucket segment
#define BKT_SH 8         // 256 nodes per bucket
#define CHUNK  256       // staged edge indices per wave-chunk

typedef __attribute__((ext_vector_type(8))) short bf8;   // 8 x bf16 (4 VGPR)
typedef __attribute__((ext_vector_type(4))) float f4;    // MFMA accumulator

__device__ __forceinline__ unsigned int f2bf(float x) {  // RNE
  unsigned int u = __float_as_uint(x);
  return (u + 0x7FFFu + ((u >> 16) & 1u)) >> 16;
}
__device__ __forceinline__ float bflo(unsigned int u) { return __uint_as_float(u << 16); }
__device__ __forceinline__ float bfhi(unsigned int u) { return __uint_as_float(u & 0xFFFF0000u); }

// ---------------- CSR build ----------------
// Blocks < nseg: LDS-hist their 4096-edge segment -> part[b][nbkt] (plain
// contiguous stores). All blocks: grid-stride fp32->bf16 convert of x.
__global__ void bhist_cvt_k(const int* __restrict__ dsti, int* __restrict__ part,
                            int ne, const float* __restrict__ x,
                            unsigned short* __restrict__ xb, int n4,
                            int nbkt, int nseg) {
  __shared__ int lh[512];
  const int b = blockIdx.x, t = threadIdx.x;
  if (b < nseg) {
    for (int i = t; i < nbkt; i += 256) lh[i] = 0;
    __syncthreads();
    const int base = b * B1_EPB;
    const int m = min(B1_EPB, ne - base);
    for (int i = t; i < m; i += 256) atomicAdd(&lh[dsti[base + i] >> BKT_SH], 1);
    __syncthreads();
    for (int i = t; i < nbkt; i += 256) part[b * nbkt + i] = lh[i];
  }
  const int gid = b * 256 + t, gst = gridDim.x * 256;
  for (int j = gid; j < n4; j += gst) {
    float4 v = ((const float4*)x)[j];
    ushort4 o;
    o.x = (unsigned short)f2bf(v.x); o.y = (unsigned short)f2bf(v.y);
    o.z = (unsigned short)f2bf(v.z); o.w = (unsigned short)f2bf(v.w);
    ((ushort4*)xb)[j] = o;
  }
}

// Single block: per-bucket totals (sum over segments) -> exclusive scan.
__global__ void bscan_k(const int* __restrict__ part, int* __restrict__ bbase,
                        int* __restrict__ bcur, int nbkt, int nseg, int ne) {
  __shared__ int sh[512];
  const int t = threadIdx.x;
  int s = 0;
  if (t < nbkt)
    for (int b = 0; b < nseg; ++b) s += part[b * nbkt + t];
  sh[t] = s; __syncthreads();
  for (int o = 1; o < 512; o <<= 1) {
    int v = (t >= o) ? sh[t - o] : 0; __syncthreads();
    sh[t] += v; __syncthreads();
  }
  if (t < nbkt) { int e = sh[t] - s; bbase[t] = e; bcur[t] = e; }
  if (t == 0) bbase[nbkt] = ne;
}

// Scatter (src,dst) into per-bucket regions of ebuf. Per-(block,bin) runs are
// contiguous & single-CU -> partial stores merge in that CU's L2.
__global__ void bucket_k(const int* __restrict__ srci, const int* __restrict__ dsti,
                         int* __restrict__ bcur, uint2* __restrict__ ebuf,
                         int ne, int nbkt) {
  __shared__ int lhist[512], lbase[512];
  const int t = threadIdx.x;
  const int base = blockIdx.x * B1_EPB;
  const int m = min(B1_EPB, ne - base);
  for (int i = t; i < nbkt; i += 256) lhist[i] = 0;
  __syncthreads();
  for (int i = t; i < m; i += 256) atomicAdd(&lhist[dsti[base + i] >> BKT_SH], 1);
  __syncthreads();
  for (int i = t; i < nbkt; i += 256) {
    int c = lhist[i];
    lbase[i] = c ? atomicAdd(&bcur[i], c) : 0;
  }
  __syncthreads();
  for (int i = t; i < nbkt; i += 256) lhist[i] = 0;   // reuse as local cursor
  __syncthreads();
  for (int i = t; i < m; i += 256) {
    const int s = srci[base + i], d = dsti[base + i];
    const int b = d >> BKT_SH;
    const int p = lbase[b] + atomicAdd(&lhist[b], 1);
    ebuf[p] = make_uint2((unsigned)s, (unsigned)d);
  }
}

// One block per 256-node bucket: LDS hist of (dst&255) -> block scan ->
// row_off (coalesced write) -> scatter src into private ssrc region.
__global__ void fillb_k(const uint2* __restrict__ ebuf, const int* __restrict__ bbase,
                        int* __restrict__ row_off, int* __restrict__ ssrc,
                        int n, int ne) {
  __shared__ int lcnt[256], lpre[256], lcur[256];
  const int b = blockIdx.x, t = threadIdx.x;
  const int v0 = b << BKT_SH;
  const int nv = min(1 << BKT_SH, n - v0);
  const int start = bbase[b], end = bbase[b + 1];
  lcnt[t] = 0; __syncthreads();
  for (int i = start + t; i < end; i += 256)
    atomicAdd(&lcnt[ebuf[i].y & ((1 << BKT_SH) - 1)], 1);
  __syncthreads();
  const int x = lcnt[t];
  lpre[t] = x; __syncthreads();
  for (int o = 1; o < 256; o <<= 1) {
    int v = (t >= o) ? lpre[t - o] : 0; __syncthreads();
    lpre[t] += v; __syncthreads();
  }
  const int excl = start + lpre[t] - x;
  lcur[t] = excl;
  if (t < nv) row_off[v0 + t] = excl;
  if (t == 0) row_off[v0 + nv] = end;   // == next bucket's base (or ne)
  __syncthreads();
  for (int i = start + t; i < end; i += 256) {
    const uint2 e = ebuf[i];
    const int p = atomicAdd(&lcur[e.y & ((1 << BKT_SH) - 1)], 1);
    ssrc[p] = (int)e.x;
  }
}

// ---------------- fused gather + MFMA GEMM (+relu | +log_softmax) ----------
// One wave per 16-node tile. Edge indices staged into LDS (coalesced); each
// quarter gathers its 4 nodes with 16 independent row loads in flight; rows
// -> LDS (144B stride) -> MFMA. C layout: col = lane&15, row = quad*4 + reg.
template <int DOUT, bool LS>
__launch_bounds__(256, 4)
__global__ void fused_k(const unsigned short* __restrict__ in,
                        const int* __restrict__ row_off, const int* __restrict__ ssrc,
                        const float* __restrict__ Wm, const float* __restrict__ bin,
                        void* __restrict__ outp, int n) {
  constexpr int NT = (DOUT + 15) / 16;
  const int lane  = threadIdx.x & 63;
  const int wslot = threadIdx.x >> 6;
  const int quad  = lane >> 4;
  const int f16i  = lane & 15;

  __shared__ char rows_raw[4][16 * 144];
  __shared__ int  sidx[4][CHUNK];
  char* my  = rows_raw[wslot];
  int*  sid = sidx[wslot];

  // B fragments: W (bf16) in registers, 2 K-steps x NT col tiles.
  bf8 bfr[2][NT];
#pragma unroll
  for (int s = 0; s < 2; ++s)
#pragma unroll
    for (int t = 0; t < NT; ++t) {
      const int c = t * 16 + f16i;
#pragma unroll
      for (int j = 0; j < 8; ++j) {
        const int k = s * 32 + quad * 8 + j;
        float wv = (c < DOUT) ? Wm[k * DOUT + c] : 0.f;
        bfr[s][t][j] = (short)f2bf(wv);
      }
    }
  float bc[NT];
#pragma unroll
  for (int t = 0; t < NT; ++t) {
    const int c = t * 16 + f16i;
    bc[t] = (c < DOUT) ? bin[c] : 0.f;
  }

  const uint2* in2 = (const uint2*)in;     // bf16 row = 16 x uint2 (128B)
  const int wid = (int)((blockIdx.x * blockDim.x + threadIdx.x) >> 6);
  const int nwv = (int)((gridDim.x * blockDim.x) >> 6);
  const int ntiles = (n + 15) >> 4;

  for (int tile = wid; tile < ntiles; tile += nwv) {
    const int v0 = tile << 4;
    // per-node ranges via one lane-load + shuffles
    const int ro_l = row_off[min(v0 + min(lane, 16), n)];
    const int base     = __shfl(ro_l, 0, 64);
    const int tile_end = __shfl(ro_l, 16, 64);
    int ns[4], nE[4];
#pragma unroll
    for (int r = 0; r < 4; ++r) {
      const int m = quad * 4 + r;
      ns[r] = __shfl(ro_l, m, 64);
      nE[r] = __shfl(ro_l, m + 1, 64);
    }

    float4 accA[4], accB[4];
#pragma unroll
    for (int r = 0; r < 4; ++r) {
      accA[r] = make_float4(0.f, 0.f, 0.f, 0.f);
      accB[r] = make_float4(0.f, 0.f, 0.f, 0.f);
    }

    for (int off = base; off < tile_end; off += CHUNK) {
      const int cend = min(tile_end, off + CHUNK);
      const int nL = cend - off;
      // stage indices: coalesced, guarded rounds
#pragma unroll
      for (int k = 0; k < CHUNK / 64; ++k) {
        const int p = off + lane + k * 64;
        if (p < cend) sid[lane + k * 64] = ssrc[p];
      }
      asm volatile("s_waitcnt lgkmcnt(0)" ::: "memory");   // cross-lane LDS RAW

#pragma unroll
      for (int r = 0; r < 4; ++r) {
        const int ls = max(ns[r], off), le = min(nE[r], cend);
        for (int c = ls; c < le; c += 16) {
          uint2 q[16];
#pragma unroll
          for (int k = 0; k < 16; ++k) {
            const int lofs = min(c - off + k, nL - 1);   // clamp LDS read
            const int s = sid[lofs];                      // quarter-broadcast
            q[k] = (c + k < le) ? in2[(size_t)s * 16 + f16i]
                                : make_uint2(0u, 0u);
          }
#pragma unroll
          for (int k = 0; k < 16; k += 2) {
            accA[r].x += bflo(q[k].x); accB[r].x += bflo(q[k + 1].x);
            accA[r].y += bfhi(q[k].x); accB[r].y += bfhi(q[k + 1].x);
            accA[r].z += bflo(q[k].y); accB[r].z += bflo(q[k + 1].y);
            accA[r].w += bfhi(q[k].y); accB[r].w += bfhi(q[k + 1].y);
          }
        }
      }
    }

    // pack rows -> LDS
#pragma unroll
    for (int r = 0; r < 4; ++r) {
      const int m = quad * 4 + r;
      uint2 p;
      p.x = f2bf(accA[r].x + accB[r].x) | (f2bf(accA[r].y + accB[r].y) << 16);
      p.y = f2bf(accA[r].z + accB[r].z) | (f2bf(accA[r].w + accB[r].w) << 16);
      *(uint2*)(my + m * 144 + f16i * 8) = p;
    }
    asm volatile("s_waitcnt lgkmcnt(0)" ::: "memory");   // cross-lane LDS RAW

    // ---- MFMA: [16 x 64] @ [64 x DOUT] ----
    bf8 a0 = *(const bf8*)(my + f16i * 144 + quad * 16);        // K 0..31
    bf8 a1 = *(const bf8*)(my + f16i * 144 + quad * 16 + 64);   // K 32..63
    f4 acc[NT];
#pragma unroll
    for (int t = 0; t < NT; ++t) {
      f4 z = {0.f, 0.f, 0.f, 0.f};
      acc[t] = __builtin_amdgcn_mfma_f32_16x16x32_bf16(a0, bfr[0][t], z, 0, 0, 0);
      acc[t] = __builtin_amdgcn_mfma_f32_16x16x32_bf16(a1, bfr[1][t], acc[t], 0, 0, 0);
    }

    // ---- epilogue ----
    if (!LS) {
      unsigned short* ob = (unsigned short*)outp;
#pragma unroll
      for (int t = 0; t < NT; ++t)
#pragma unroll
        for (int j = 0; j < 4; ++j) {
          const int v = v0 + quad * 4 + j;
          if (v < n) {
            float val = acc[t][j] + bc[t];
            ob[(size_t)v * 64 + t * 16 + f16i] =
                (unsigned short)f2bf(fmaxf(val, 0.f));
          }
        }
    } else {
      float* ob = (float*)outp;
      float val[NT][4];
#pragma unroll
      for (int t = 0; t < NT; ++t)
#pragma unroll
        for (int j = 0; j < 4; ++j) val[t][j] = acc[t][j] + bc[t];
#pragma unroll
      for (int j = 0; j < 4; ++j) {
        float mx = -INFINITY;
#pragma unroll
        for (int t = 0; t < NT; ++t)
          if (t * 16 + f16i < DOUT) mx = fmaxf(mx, val[t][j]);
#pragma unroll
        for (int o = 1; o <= 8; o <<= 1) mx = fmaxf(mx, __shfl_xor(mx, o, 64));
        float sm = 0.f;
#pragma unroll
        for (int t = 0; t < NT; ++t)
          if (t * 16 + f16i < DOUT) sm += __expf(val[t][j] - mx);
#pragma unroll
        for (int o = 1; o <= 8; o <<= 1) sm += __shfl_xor(sm, o, 64);
        const float lse = mx + __logf(sm);
        const int v = v0 + quad * 4 + j;
        if (v < n) {
#pragma unroll
          for (int t = 0; t < NT; ++t) {
            const int c = t * 16 + f16i;
            if (c < DOUT) ob[(size_t)v * DOUT + c] = val[t][j] - lse;
          }
        }
      }
    }
  }
}

extern "C" void kernel_launch(void* const* d_in, const int* in_sizes, int n_in,
                              void* d_out, int out_size, void* d_ws, size_t ws_size,
                              hipStream_t stream) {
  const float* x  = (const float*)d_in[0];
  const int*   ei = (const int*)d_in[1];   // [2, E] int32, row-major
  const float* W1 = (const float*)d_in[2];
  const float* b1 = (const float*)d_in[3];
  const float* W2 = (const float*)d_in[4];
  const float* b2 = (const float*)d_in[5];
  const float* W3 = (const float*)d_in[6];
  const float* b3 = (const float*)d_in[7];
  float* outp = (float*)d_out;

  const int n  = in_sizes[0] / 64;   // 100000
  const int ne = in_sizes[1] / 2;    // 800000
  const int* srci = ei;
  const int* dsti = ei + ne;
  const int nbkt = (n + (1 << BKT_SH) - 1) >> BKT_SH;   // 391
  const int nseg = (ne + B1_EPB - 1) / B1_EPB;          // 196

  const size_t N64 = (size_t)n * 64;
  unsigned short* xb   = (unsigned short*)d_ws;   // N*64 bf16
  unsigned short* bufA = xb + N64;                // N*64 bf16 (h1)
  unsigned short* bufB = bufA + N64;              // N*64 bf16 (h2)
  uint2* ebuf   = (uint2*)(bufB + N64);           // E x (src,dst)
  int* row_off  = (int*)(ebuf + ne);              // N+1
  int* part     = row_off + n + 1;                // nseg*nbkt
  int* bbase    = part + nseg * nbkt;             // nbkt+1
  int* bcur     = bbase + nbkt + 1;               // nbkt
  int* ssrc     = bcur + nbkt;                    // E

  const int TB = 256;
  const int fus_blocks = 1568;                    // 1 tile/wave (6250 tiles)

  // ---- CSR build + x->bf16 (4 dispatches, no memset) ----
  bhist_cvt_k<<<784, TB, 0, stream>>>(dsti, part, ne, x, xb, (int)(N64 / 4), nbkt, nseg);
  bscan_k<<<1, 512, 0, stream>>>(part, bbase, bcur, nbkt, nseg, ne);
  bucket_k<<<nseg, TB, 0, stream>>>(srci, dsti, bcur, ebuf, ne, nbkt);
  fillb_k<<<nbkt, TB, 0, stream>>>(ebuf, bbase, row_off, ssrc, n, ne);

  // ---- fused layers ----
  fused_k<64, false><<<fus_blocks, TB, 0, stream>>>(xb,   row_off, ssrc, W1, b1, bufA, n);
  fused_k<64, false><<<fus_blocks, TB, 0, stream>>>(bufA, row_off, ssrc, W2, b2, bufB, n);
  fused_k<47, true ><<<fus_blocks, TB, 0, stream>>>(bufB, row_off, ssrc, W3, b3, outp, n);
}

// Round 9
// 249.819 us; speedup vs baseline: 1.1303x; 1.1303x over previous
//
#include <hip/hip_runtime.h>
#include <cmath>

// ---------------------------------------------------------------------------
// 3-layer GCN, atomic-free aggregate, bf16 data path, MFMA epilogue.
// CSR build (4 dispatches, no memset):
//   bhist_cvt_k : per-4096-edge-segment LDS hist -> part[seg][bkt] (plain
//                 stores, no init needed) + grid-stride x->bf16 convert
//   bscan_k     : 1 block: sum part over segs, scan 391 buckets -> bbase/bcur
//   bucket_k    : scatter (src,dst) -> per-bucket regions of ebuf (single-
//                 block-owned lines; R5 showed random 4B stores cost 64B each)
//   fillb_k     : per bucket: LDS 256-node hist + block scan -> row_off
//                 (coalesced) + scatter src -> block-private ssrc region
// Fused layer: stage tile's edge indices into LDS, 8 row-loads in flight per
// node (R8's 16-deep spilled: q[16]+accs+Wfrags > budget -> 50MB scratch
// writes, dur 49->63us; 8-deep is the no-spill sweet spot at VGPR~40-52),
// fp32 accumulate -> bf16 rows in LDS -> mfma_f32_16x16x32_bf16 -> bias
// (+relu->bf16 | +log_softmax->fp32).
// ---------------------------------------------------------------------------

#define B1_EPB 4096      // edges per histogram/bucket segment
#define BKT_SH 8         // 256 nodes per bucket
#define CHUNK  256       // staged edge indices per wave-chunk

typedef __attribute__((ext_vector_type(8))) short bf8;   // 8 x bf16 (4 VGPR)
typedef __attribute__((ext_vector_type(4))) float f4;    // MFMA accumulator

__device__ __forceinline__ unsigned int f2bf(float x) {  // RNE
  unsigned int u = __float_as_uint(x);
  return (u + 0x7FFFu + ((u >> 16) & 1u)) >> 16;
}
__device__ __forceinline__ float bflo(unsigned int u) { return __uint_as_float(u << 16); }
__device__ __forceinline__ float bfhi(unsigned int u) { return __uint_as_float(u & 0xFFFF0000u); }

// ---------------- CSR build ----------------
__global__ void bhist_cvt_k(const int* __restrict__ dsti, int* __restrict__ part,
                            int ne, const float* __restrict__ x,
                            unsigned short* __restrict__ xb, int n4,
                            int nbkt, int nseg) {
  __shared__ int lh[512];
  const int b = blockIdx.x, t = threadIdx.x;
  if (b < nseg) {
    for (int i = t; i < nbkt; i += 256) lh[i] = 0;
    __syncthreads();
    const int base = b * B1_EPB;
    const int m = min(B1_EPB, ne - base);
    for (int i = t; i < m; i += 256) atomicAdd(&lh[dsti[base + i] >> BKT_SH], 1);
    __syncthreads();
    for (int i = t; i < nbkt; i += 256) part[b * nbkt + i] = lh[i];
  }
  const int gid = b * 256 + t, gst = gridDim.x * 256;
  for (int j = gid; j < n4; j += gst) {
    float4 v = ((const float4*)x)[j];
    ushort4 o;
    o.x = (unsigned short)f2bf(v.x); o.y = (unsigned short)f2bf(v.y);
    o.z = (unsigned short)f2bf(v.z); o.w = (unsigned short)f2bf(v.w);
    ((ushort4*)xb)[j] = o;
  }
}

// Single block: per-bucket totals (sum over segments) -> exclusive scan.
__global__ void bscan_k(const int* __restrict__ part, int* __restrict__ bbase,
                        int* __restrict__ bcur, int nbkt, int nseg, int ne) {
  __shared__ int sh[512];
  const int t = threadIdx.x;
  int s = 0;
  if (t < nbkt)
    for (int b = 0; b < nseg; ++b) s += part[b * nbkt + t];
  sh[t] = s; __syncthreads();
  for (int o = 1; o < 512; o <<= 1) {
    int v = (t >= o) ? sh[t - o] : 0; __syncthreads();
    sh[t] += v; __syncthreads();
  }
  if (t < nbkt) { int e = sh[t] - s; bbase[t] = e; bcur[t] = e; }
  if (t == 0) bbase[nbkt] = ne;
}

// Scatter (src,dst) into per-bucket regions of ebuf. Per-(block,bin) runs are
// contiguous & single-CU -> partial stores merge in that CU's L2.
__global__ void bucket_k(const int* __restrict__ srci, const int* __restrict__ dsti,
                         int* __restrict__ bcur, uint2* __restrict__ ebuf,
                         int ne, int nbkt) {
  __shared__ int lhist[512], lbase[512];
  const int t = threadIdx.x;
  const int base = blockIdx.x * B1_EPB;
  const int m = min(B1_EPB, ne - base);
  for (int i = t; i < nbkt; i += 256) lhist[i] = 0;
  __syncthreads();
  for (int i = t; i < m; i += 256) atomicAdd(&lhist[dsti[base + i] >> BKT_SH], 1);
  __syncthreads();
  for (int i = t; i < nbkt; i += 256) {
    int c = lhist[i];
    lbase[i] = c ? atomicAdd(&bcur[i], c) : 0;
  }
  __syncthreads();
  for (int i = t; i < nbkt; i += 256) lhist[i] = 0;   // reuse as local cursor
  __syncthreads();
  for (int i = t; i < m; i += 256) {
    const int s = srci[base + i], d = dsti[base + i];
    const int b = d >> BKT_SH;
    const int p = lbase[b] + atomicAdd(&lhist[b], 1);
    ebuf[p] = make_uint2((unsigned)s, (unsigned)d);
  }
}

// One block per 256-node bucket: LDS hist of (dst&255) -> block scan ->
// row_off (coalesced write) -> scatter src into private ssrc region.
__global__ void fillb_k(const uint2* __restrict__ ebuf, const int* __restrict__ bbase,
                        int* __restrict__ row_off, int* __restrict__ ssrc,
                        int n, int ne) {
  __shared__ int lcnt[256], lpre[256], lcur[256];
  const int b = blockIdx.x, t = threadIdx.x;
  const int v0 = b << BKT_SH;
  const int nv = min(1 << BKT_SH, n - v0);
  const int start = bbase[b], end = bbase[b + 1];
  lcnt[t] = 0; __syncthreads();
  for (int i = start + t; i < end; i += 256)
    atomicAdd(&lcnt[ebuf[i].y & ((1 << BKT_SH) - 1)], 1);
  __syncthreads();
  const int x = lcnt[t];
  lpre[t] = x; __syncthreads();
  for (int o = 1; o < 256; o <<= 1) {
    int v = (t >= o) ? lpre[t - o] : 0; __syncthreads();
    lpre[t] += v; __syncthreads();
  }
  const int excl = start + lpre[t] - x;
  lcur[t] = excl;
  if (t < nv) row_off[v0 + t] = excl;
  if (t == 0) row_off[v0 + nv] = end;   // == next bucket's base (or ne)
  __syncthreads();
  for (int i = start + t; i < end; i += 256) {
    const uint2 e = ebuf[i];
    const int p = atomicAdd(&lcur[e.y & ((1 << BKT_SH) - 1)], 1);
    ssrc[p] = (int)e.x;
  }
}

// ---------------- fused gather + MFMA GEMM (+relu | +log_softmax) ----------
// One wave per 16-node tile. Edge indices staged into LDS (coalesced); each
// quarter gathers its 4 nodes with 8 independent row loads in flight; rows
// -> LDS (144B stride) -> MFMA. C layout: col = lane&15, row = quad*4 + reg.
template <int DOUT, bool LS>
__launch_bounds__(256, 4)
__global__ void fused_k(const unsigned short* __restrict__ in,
                        const int* __restrict__ row_off, const int* __restrict__ ssrc,
                        const float* __restrict__ Wm, const float* __restrict__ bin,
                        void* __restrict__ outp, int n) {
  constexpr int NT = (DOUT + 15) / 16;
  const int lane  = threadIdx.x & 63;
  const int wslot = threadIdx.x >> 6;
  const int quad  = lane >> 4;
  const int f16i  = lane & 15;

  __shared__ char rows_raw[4][16 * 144];
  __shared__ int  sidx[4][CHUNK];
  char* my  = rows_raw[wslot];
  int*  sid = sidx[wslot];

  // B fragments: W (bf16) in registers, 2 K-steps x NT col tiles.
  bf8 bfr[2][NT];
#pragma unroll
  for (int s = 0; s < 2; ++s)
#pragma unroll
    for (int t = 0; t < NT; ++t) {
      const int c = t * 16 + f16i;
#pragma unroll
      for (int j = 0; j < 8; ++j) {
        const int k = s * 32 + quad * 8 + j;
        float wv = (c < DOUT) ? Wm[k * DOUT + c] : 0.f;
        bfr[s][t][j] = (short)f2bf(wv);
      }
    }
  float bc[NT];
#pragma unroll
  for (int t = 0; t < NT; ++t) {
    const int c = t * 16 + f16i;
    bc[t] = (c < DOUT) ? bin[c] : 0.f;
  }

  const uint2* in2 = (const uint2*)in;     // bf16 row = 16 x uint2 (128B)
  const int wid = (int)((blockIdx.x * blockDim.x + threadIdx.x) >> 6);
  const int nwv = (int)((gridDim.x * blockDim.x) >> 6);
  const int ntiles = (n + 15) >> 4;

  for (int tile = wid; tile < ntiles; tile += nwv) {
    const int v0 = tile << 4;
    // per-node ranges via one lane-load + shuffles
    const int ro_l = row_off[min(v0 + min(lane, 16), n)];
    const int base     = __shfl(ro_l, 0, 64);
    const int tile_end = __shfl(ro_l, 16, 64);
    int ns[4], nE[4];
#pragma unroll
    for (int r = 0; r < 4; ++r) {
      const int m = quad * 4 + r;
      ns[r] = __shfl(ro_l, m, 64);
      nE[r] = __shfl(ro_l, m + 1, 64);
    }

    float4 accA[4], accB[4];
#pragma unroll
    for (int r = 0; r < 4; ++r) {
      accA[r] = make_float4(0.f, 0.f, 0.f, 0.f);
      accB[r] = make_float4(0.f, 0.f, 0.f, 0.f);
    }

    for (int off = base; off < tile_end; off += CHUNK) {
      const int cend = min(tile_end, off + CHUNK);
      const int nL = cend - off;
      // stage indices: coalesced, guarded rounds
#pragma unroll
      for (int k = 0; k < CHUNK / 64; ++k) {
        const int p = off + lane + k * 64;
        if (p < cend) sid[lane + k * 64] = ssrc[p];
      }
      asm volatile("s_waitcnt lgkmcnt(0)" ::: "memory");   // cross-lane LDS RAW

#pragma unroll
      for (int r = 0; r < 4; ++r) {
        const int ls = max(ns[r], off), le = min(nE[r], cend);
        for (int c = ls; c < le; c += 8) {
          uint2 q[8];
#pragma unroll
          for (int k = 0; k < 8; ++k) {
            const int lofs = min(c - off + k, nL - 1);   // clamp LDS read
            const int s = sid[lofs];                      // quarter-broadcast
            q[k] = (c + k < le) ? in2[(size_t)s * 16 + f16i]
                                : make_uint2(0u, 0u);
          }
#pragma unroll
          for (int k = 0; k < 8; k += 2) {
            accA[r].x += bflo(q[k].x); accB[r].x += bflo(q[k + 1].x);
            accA[r].y += bfhi(q[k].x); accB[r].y += bfhi(q[k + 1].x);
            accA[r].z += bflo(q[k].y); accB[r].z += bflo(q[k + 1].y);
            accA[r].w += bfhi(q[k].y); accB[r].w += bfhi(q[k + 1].y);
          }
        }
      }
    }

    // pack rows -> LDS
#pragma unroll
    for (int r = 0; r < 4; ++r) {
      const int m = quad * 4 + r;
      uint2 p;
      p.x = f2bf(accA[r].x + accB[r].x) | (f2bf(accA[r].y + accB[r].y) << 16);
      p.y = f2bf(accA[r].z + accB[r].z) | (f2bf(accA[r].w + accB[r].w) << 16);
      *(uint2*)(my + m * 144 + f16i * 8) = p;
    }
    asm volatile("s_waitcnt lgkmcnt(0)" ::: "memory");   // cross-lane LDS RAW

    // ---- MFMA: [16 x 64] @ [64 x DOUT] ----
    bf8 a0 = *(const bf8*)(my + f16i * 144 + quad * 16);        // K 0..31
    bf8 a1 = *(const bf8*)(my + f16i * 144 + quad * 16 + 64);   // K 32..63
    f4 acc[NT];
#pragma unroll
    for (int t = 0; t < NT; ++t) {
      f4 z = {0.f, 0.f, 0.f, 0.f};
      acc[t] = __builtin_amdgcn_mfma_f32_16x16x32_bf16(a0, bfr[0][t], z, 0, 0, 0);
      acc[t] = __builtin_amdgcn_mfma_f32_16x16x32_bf16(a1, bfr[1][t], acc[t], 0, 0, 0);
    }

    // ---- epilogue ----
    if (!LS) {
      unsigned short* ob = (unsigned short*)outp;
#pragma unroll
      for (int t = 0; t < NT; ++t)
#pragma unroll
        for (int j = 0; j < 4; ++j) {
          const int v = v0 + quad * 4 + j;
          if (v < n) {
            float val = acc[t][j] + bc[t];
            ob[(size_t)v * 64 + t * 16 + f16i] =
                (unsigned short)f2bf(fmaxf(val, 0.f));
          }
        }
    } else {
      float* ob = (float*)outp;
      float val[NT][4];
#pragma unroll
      for (int t = 0; t < NT; ++t)
#pragma unroll
        for (int j = 0; j < 4; ++j) val[t][j] = acc[t][j] + bc[t];
#pragma unroll
      for (int j = 0; j < 4; ++j) {
        float mx = -INFINITY;
#pragma unroll
        for (int t = 0; t < NT; ++t)
          if (t * 16 + f16i < DOUT) mx = fmaxf(mx, val[t][j]);
#pragma unroll
        for (int o = 1; o <= 8; o <<= 1) mx = fmaxf(mx, __shfl_xor(mx, o, 64));
        float sm = 0.f;
#pragma unroll
        for (int t = 0; t < NT; ++t)
          if (t * 16 + f16i < DOUT) sm += __expf(val[t][j] - mx);
#pragma unroll
        for (int o = 1; o <= 8; o <<= 1) sm += __shfl_xor(sm, o, 64);
        const float lse = mx + __logf(sm);
        const int v = v0 + quad * 4 + j;
        if (v < n) {
#pragma unroll
          for (int t = 0; t < NT; ++t) {
            const int c = t * 16 + f16i;
            if (c < DOUT) ob[(size_t)v * DOUT + c] = val[t][j] - lse;
          }
        }
      }
    }
  }
}

extern "C" void kernel_launch(void* const* d_in, const int* in_sizes, int n_in,
                              void* d_out, int out_size, void* d_ws, size_t ws_size,
                              hipStream_t stream) {
  const float* x  = (const float*)d_in[0];
  const int*   ei = (const int*)d_in[1];   // [2, E] int32, row-major
  const float* W1 = (const float*)d_in[2];
  const float* b1 = (const float*)d_in[3];
  const float* W2 = (const float*)d_in[4];
  const float* b2 = (const float*)d_in[5];
  const float* W3 = (const float*)d_in[6];
  const float* b3 = (const float*)d_in[7];
  float* outp = (float*)d_out;

  const int n  = in_sizes[0] / 64;   // 100000
  const int ne = in_sizes[1] / 2;    // 800000
  const int* srci = ei;
  const int* dsti = ei + ne;
  const int nbkt = (n + (1 << BKT_SH) - 1) >> BKT_SH;   // 391
  const int nseg = (ne + B1_EPB - 1) / B1_EPB;          // 196

  const size_t N64 = (size_t)n * 64;
  unsigned short* xb   = (unsigned short*)d_ws;   // N*64 bf16
  unsigned short* bufA = xb + N64;                // N*64 bf16 (h1)
  unsigned short* bufB = bufA + N64;              // N*64 bf16 (h2)
  uint2* ebuf   = (uint2*)(bufB + N64);           // E x (src,dst)
  int* row_off  = (int*)(ebuf + ne);              // N+1
  int* part     = row_off + n + 1;                // nseg*nbkt
  int* bbase    = part + nseg * nbkt;             // nbkt+1
  int* bcur     = bbase + nbkt + 1;               // nbkt
  int* ssrc     = bcur + nbkt;                    // E

  const int TB = 256;
  const int fus_blocks = 1568;                    // 1 tile/wave (6250 tiles)

  // ---- CSR build + x->bf16 (4 dispatches, no memset) ----
  bhist_cvt_k<<<784, TB, 0, stream>>>(dsti, part, ne, x, xb, (int)(N64 / 4), nbkt, nseg);
  bscan_k<<<1, 512, 0, stream>>>(part, bbase, bcur, nbkt, nseg, ne);
  bucket_k<<<nseg, TB, 0, stream>>>(srci, dsti, bcur, ebuf, ne, nbkt);
  fillb_k<<<nbkt, TB, 0, stream>>>(ebuf, bbase, row_off, ssrc, n, ne);

  // ---- fused layers ----
  fused_k<64, false><<<fus_blocks, TB, 0, stream>>>(xb,   row_off, ssrc, W1, b1, bufA, n);
  fused_k<64, false><<<fus_blocks, TB, 0, stream>>>(bufA, row_off, ssrc, W2, b2, bufB, n);
  fused_k<47, true ><<<fus_blocks, TB, 0, stream>>>(bufB, row_off, ssrc, W3, b3, outp, n);
}

// Round 10
// 208.208 us; speedup vs baseline: 1.3561x; 1.1999x over previous
//
#include <hip/hip_runtime.h>
#include <cmath>

// ---------------------------------------------------------------------------
// 3-layer GCN, atomic-free aggregate, bf16 data path, MFMA epilogue.
// CSR build (4 dispatches, no memset):
//   bhist_cvt_k : per-4096-edge-segment LDS hist -> part[seg][512] (padded
//                 stride so bscan reads are coalesced) + x->bf16 convert
//   bscan_k     : 1 block: per-bucket totals via 8-deep-unrolled coalesced
//                 sum over segments (R9's strided 196-deep serial chain was
//                 54us of pure latency), then 512-wide scan -> bbase/bcur
//   bucket_k    : scatter (src,dst) -> per-bucket regions of ebuf (single-
//                 block-owned lines; R5 showed random 4B stores cost 64B each)
//   fillb_k     : per bucket: LDS 256-node hist + block scan -> row_off
//                 (coalesced) + scatter src -> block-private ssrc region
// Fused layer: stage tile's edge indices into LDS, 8 row-loads in flight per
// node (16-deep spills: R8 showed q[16]+accs+Wfrags -> 50MB scratch traffic),
// fp32 accumulate -> bf16 rows in LDS -> mfma_f32_16x16x32_bf16 -> bias
// (+relu->bf16 | +log_softmax->fp32).
// ---------------------------------------------------------------------------

#define B1_EPB 4096      // edges per histogram/bucket segment
#define BKT_SH 8         // 256 nodes per bucket
#define CHUNK  256       // staged edge indices per wave-chunk
#define PSTRIDE 512      // padded part row stride (coalesced bscan)

typedef __attribute__((ext_vector_type(8))) short bf8;   // 8 x bf16 (4 VGPR)
typedef __attribute__((ext_vector_type(4))) float f4;    // MFMA accumulator

__device__ __forceinline__ unsigned int f2bf(float x) {  // RNE
  unsigned int u = __float_as_uint(x);
  return (u + 0x7FFFu + ((u >> 16) & 1u)) >> 16;
}
__device__ __forceinline__ float bflo(unsigned int u) { return __uint_as_float(u << 16); }
__device__ __forceinline__ float bfhi(unsigned int u) { return __uint_as_float(u & 0xFFFF0000u); }

// ---------------- CSR build ----------------
__global__ void bhist_cvt_k(const int* __restrict__ dsti, int* __restrict__ part,
                            int ne, const float* __restrict__ x,
                            unsigned short* __restrict__ xb, int n4,
                            int nbkt, int nseg) {
  __shared__ int lh[PSTRIDE];
  const int b = blockIdx.x, t = threadIdx.x;
  if (b < nseg) {
    for (int i = t; i < PSTRIDE; i += 256) lh[i] = 0;
    __syncthreads();
    const int base = b * B1_EPB;
    const int m = min(B1_EPB, ne - base);
    for (int i = t; i < m; i += 256) atomicAdd(&lh[dsti[base + i] >> BKT_SH], 1);
    __syncthreads();
    for (int i = t; i < PSTRIDE; i += 256) part[b * PSTRIDE + i] = lh[i];
  }
  const int gid = b * 256 + t, gst = gridDim.x * 256;
  for (int j = gid; j < n4; j += gst) {
    float4 v = ((const float4*)x)[j];
    ushort4 o;
    o.x = (unsigned short)f2bf(v.x); o.y = (unsigned short)f2bf(v.y);
    o.z = (unsigned short)f2bf(v.z); o.w = (unsigned short)f2bf(v.w);
    ((ushort4*)xb)[j] = o;
  }
}

// Single block: per-bucket totals (coalesced, 8 loads in flight) -> scan.
__global__ void bscan_k(const int* __restrict__ part, int* __restrict__ bbase,
                        int* __restrict__ bcur, int nbkt, int nseg, int ne) {
  __shared__ int sh[512];
  const int t = threadIdx.x;
  int s0 = 0, s1 = 0, s2 = 0, s3 = 0, s4 = 0, s5 = 0, s6 = 0, s7 = 0;
  int b = 0;
  for (; b + 7 < nseg; b += 8) {
    s0 += part[(b + 0) * PSTRIDE + t];
    s1 += part[(b + 1) * PSTRIDE + t];
    s2 += part[(b + 2) * PSTRIDE + t];
    s3 += part[(b + 3) * PSTRIDE + t];
    s4 += part[(b + 4) * PSTRIDE + t];
    s5 += part[(b + 5) * PSTRIDE + t];
    s6 += part[(b + 6) * PSTRIDE + t];
    s7 += part[(b + 7) * PSTRIDE + t];
  }
  for (; b < nseg; ++b) s0 += part[b * PSTRIDE + t];
  const int s = ((s0 + s1) + (s2 + s3)) + ((s4 + s5) + (s6 + s7));
  sh[t] = s; __syncthreads();
  for (int o = 1; o < 512; o <<= 1) {
    int v = (t >= o) ? sh[t - o] : 0; __syncthreads();
    sh[t] += v; __syncthreads();
  }
  if (t < nbkt) { int e = sh[t] - s; bbase[t] = e; bcur[t] = e; }
  if (t == 0) bbase[nbkt] = ne;
}

// Scatter (src,dst) into per-bucket regions of ebuf. Per-(block,bin) runs are
// contiguous & single-CU -> partial stores merge in that CU's L2.
__global__ void bucket_k(const int* __restrict__ srci, const int* __restrict__ dsti,
                         int* __restrict__ bcur, uint2* __restrict__ ebuf,
                         int ne, int nbkt) {
  __shared__ int lhist[512], lbase[512];
  const int t = threadIdx.x;
  const int base = blockIdx.x * B1_EPB;
  const int m = min(B1_EPB, ne - base);
  for (int i = t; i < nbkt; i += 256) lhist[i] = 0;
  __syncthreads();
  for (int i = t; i < m; i += 256) atomicAdd(&lhist[dsti[base + i] >> BKT_SH], 1);
  __syncthreads();
  for (int i = t; i < nbkt; i += 256) {
    int c = lhist[i];
    lbase[i] = c ? atomicAdd(&bcur[i], c) : 0;
  }
  __syncthreads();
  for (int i = t; i < nbkt; i += 256) lhist[i] = 0;   // reuse as local cursor
  __syncthreads();
  for (int i = t; i < m; i += 256) {
    const int s = srci[base + i], d = dsti[base + i];
    const int b = d >> BKT_SH;
    const int p = lbase[b] + atomicAdd(&lhist[b], 1);
    ebuf[p] = make_uint2((unsigned)s, (unsigned)d);
  }
}

// One block per 256-node bucket: LDS hist of (dst&255) -> block scan ->
// row_off (coalesced write) -> scatter src into private ssrc region.
__global__ void fillb_k(const uint2* __restrict__ ebuf, const int* __restrict__ bbase,
                        int* __restrict__ row_off, int* __restrict__ ssrc,
                        int n, int ne) {
  __shared__ int lcnt[256], lpre[256], lcur[256];
  const int b = blockIdx.x, t = threadIdx.x;
  const int v0 = b << BKT_SH;
  const int nv = min(1 << BKT_SH, n - v0);
  const int start = bbase[b], end = bbase[b + 1];
  lcnt[t] = 0; __syncthreads();
  for (int i = start + t; i < end; i += 256)
    atomicAdd(&lcnt[ebuf[i].y & ((1 << BKT_SH) - 1)], 1);
  __syncthreads();
  const int x = lcnt[t];
  lpre[t] = x; __syncthreads();
  for (int o = 1; o < 256; o <<= 1) {
    int v = (t >= o) ? lpre[t - o] : 0; __syncthreads();
    lpre[t] += v; __syncthreads();
  }
  const int excl = start + lpre[t] - x;
  lcur[t] = excl;
  if (t < nv) row_off[v0 + t] = excl;
  if (t == 0) row_off[v0 + nv] = end;   // == next bucket's base (or ne)
  __syncthreads();
  for (int i = start + t; i < end; i += 256) {
    const uint2 e = ebuf[i];
    const int p = atomicAdd(&lcur[e.y & ((1 << BKT_SH) - 1)], 1);
    ssrc[p] = (int)e.x;
  }
}

// ---------------- fused gather + MFMA GEMM (+relu | +log_softmax) ----------
// One wave per 16-node tile. Edge indices staged into LDS (coalesced); each
// quarter gathers its 4 nodes with 8 independent row loads in flight; rows
// -> LDS (144B stride) -> MFMA. C layout: col = lane&15, row = quad*4 + reg.
template <int DOUT, bool LS>
__launch_bounds__(256, 4)
__global__ void fused_k(const unsigned short* __restrict__ in,
                        const int* __restrict__ row_off, const int* __restrict__ ssrc,
                        const float* __restrict__ Wm, const float* __restrict__ bin,
                        void* __restrict__ outp, int n) {
  constexpr int NT = (DOUT + 15) / 16;
  const int lane  = threadIdx.x & 63;
  const int wslot = threadIdx.x >> 6;
  const int quad  = lane >> 4;
  const int f16i  = lane & 15;

  __shared__ char rows_raw[4][16 * 144];
  __shared__ int  sidx[4][CHUNK];
  char* my  = rows_raw[wslot];
  int*  sid = sidx[wslot];

  // B fragments: W (bf16) in registers, 2 K-steps x NT col tiles.
  bf8 bfr[2][NT];
#pragma unroll
  for (int s = 0; s < 2; ++s)
#pragma unroll
    for (int t = 0; t < NT; ++t) {
      const int c = t * 16 + f16i;
#pragma unroll
      for (int j = 0; j < 8; ++j) {
        const int k = s * 32 + quad * 8 + j;
        float wv = (c < DOUT) ? Wm[k * DOUT + c] : 0.f;
        bfr[s][t][j] = (short)f2bf(wv);
      }
    }
  float bc[NT];
#pragma unroll
  for (int t = 0; t < NT; ++t) {
    const int c = t * 16 + f16i;
    bc[t] = (c < DOUT) ? bin[c] : 0.f;
  }

  const uint2* in2 = (const uint2*)in;     // bf16 row = 16 x uint2 (128B)
  const int wid = (int)((blockIdx.x * blockDim.x + threadIdx.x) >> 6);
  const int nwv = (int)((gridDim.x * blockDim.x) >> 6);
  const int ntiles = (n + 15) >> 4;

  for (int tile = wid; tile < ntiles; tile += nwv) {
    const int v0 = tile << 4;
    // per-node ranges via one lane-load + shuffles
    const int ro_l = row_off[min(v0 + min(lane, 16), n)];
    const int base     = __shfl(ro_l, 0, 64);
    const int tile_end = __shfl(ro_l, 16, 64);
    int ns[4], nE[4];
#pragma unroll
    for (int r = 0; r < 4; ++r) {
      const int m = quad * 4 + r;
      ns[r] = __shfl(ro_l, m, 64);
      nE[r] = __shfl(ro_l, m + 1, 64);
    }

    float4 accA[4], accB[4];
#pragma unroll
    for (int r = 0; r < 4; ++r) {
      accA[r] = make_float4(0.f, 0.f, 0.f, 0.f);
      accB[r] = make_float4(0.f, 0.f, 0.f, 0.f);
    }

    for (int off = base; off < tile_end; off += CHUNK) {
      const int cend = min(tile_end, off + CHUNK);
      const int nL = cend - off;
      // stage indices: coalesced, guarded rounds
#pragma unroll
      for (int k = 0; k < CHUNK / 64; ++k) {
        const int p = off + lane + k * 64;
        if (p < cend) sid[lane + k * 64] = ssrc[p];
      }
      asm volatile("s_waitcnt lgkmcnt(0)" ::: "memory");   // cross-lane LDS RAW

#pragma unroll
      for (int r = 0; r < 4; ++r) {
        const int ls = max(ns[r], off), le = min(nE[r], cend);
        for (int c = ls; c < le; c += 8) {
          uint2 q[8];
#pragma unroll
          for (int k = 0; k < 8; ++k) {
            const int lofs = min(c - off + k, nL - 1);   // clamp LDS read
            const int s = sid[lofs];                      // quarter-broadcast
            q[k] = (c + k < le) ? in2[(size_t)s * 16 + f16i]
                                : make_uint2(0u, 0u);
          }
#pragma unroll
          for (int k = 0; k < 8; k += 2) {
            accA[r].x += bflo(q[k].x); accB[r].x += bflo(q[k + 1].x);
            accA[r].y += bfhi(q[k].x); accB[r].y += bfhi(q[k + 1].x);
            accA[r].z += bflo(q[k].y); accB[r].z += bflo(q[k + 1].y);
            accA[r].w += bfhi(q[k].y); accB[r].w += bfhi(q[k + 1].y);
          }
        }
      }
    }

    // pack rows -> LDS
#pragma unroll
    for (int r = 0; r < 4; ++r) {
      const int m = quad * 4 + r;
      uint2 p;
      p.x = f2bf(accA[r].x + accB[r].x) | (f2bf(accA[r].y + accB[r].y) << 16);
      p.y = f2bf(accA[r].z + accB[r].z) | (f2bf(accA[r].w + accB[r].w) << 16);
      *(uint2*)(my + m * 144 + f16i * 8) = p;
    }
    asm volatile("s_waitcnt lgkmcnt(0)" ::: "memory");   // cross-lane LDS RAW

    // ---- MFMA: [16 x 64] @ [64 x DOUT] ----
    bf8 a0 = *(const bf8*)(my + f16i * 144 + quad * 16);        // K 0..31
    bf8 a1 = *(const bf8*)(my + f16i * 144 + quad * 16 + 64);   // K 32..63
    f4 acc[NT];
#pragma unroll
    for (int t = 0; t < NT; ++t) {
      f4 z = {0.f, 0.f, 0.f, 0.f};
      acc[t] = __builtin_amdgcn_mfma_f32_16x16x32_bf16(a0, bfr[0][t], z, 0, 0, 0);
      acc[t] = __builtin_amdgcn_mfma_f32_16x16x32_bf16(a1, bfr[1][t], acc[t], 0, 0, 0);
    }

    // ---- epilogue ----
    if (!LS) {
      unsigned short* ob = (unsigned short*)outp;
#pragma unroll
      for (int t = 0; t < NT; ++t)
#pragma unroll
        for (int j = 0; j < 4; ++j) {
          const int v = v0 + quad * 4 + j;
          if (v < n) {
            float val = acc[t][j] + bc[t];
            ob[(size_t)v * 64 + t * 16 + f16i] =
                (unsigned short)f2bf(fmaxf(val, 0.f));
          }
        }
    } else {
      float* ob = (float*)outp;
      float val[NT][4];
#pragma unroll
      for (int t = 0; t < NT; ++t)
#pragma unroll
        for (int j = 0; j < 4; ++j) val[t][j] = acc[t][j] + bc[t];
#pragma unroll
      for (int j = 0; j < 4; ++j) {
        float mx = -INFINITY;
#pragma unroll
        for (int t = 0; t < NT; ++t)
          if (t * 16 + f16i < DOUT) mx = fmaxf(mx, val[t][j]);
#pragma unroll
        for (int o = 1; o <= 8; o <<= 1) mx = fmaxf(mx, __shfl_xor(mx, o, 64));
        float sm = 0.f;
#pragma unroll
        for (int t = 0; t < NT; ++t)
          if (t * 16 + f16i < DOUT) sm += __expf(val[t][j] - mx);
#pragma unroll
        for (int o = 1; o <= 8; o <<= 1) sm += __shfl_xor(sm, o, 64);
        const float lse = mx + __logf(sm);
        const int v = v0 + quad * 4 + j;
        if (v < n) {
#pragma unroll
          for (int t = 0; t < NT; ++t) {
            const int c = t * 16 + f16i;
            if (c < DOUT) ob[(size_t)v * DOUT + c] = val[t][j] - lse;
          }
        }
      }
    }
  }
}

extern "C" void kernel_launch(void* const* d_in, const int* in_sizes, int n_in,
                              void* d_out, int out_size, void* d_ws, size_t ws_size,
                              hipStream_t stream) {
  const float* x  = (const float*)d_in[0];
  const int*   ei = (const int*)d_in[1];   // [2, E] int32, row-major
  const float* W1 = (const float*)d_in[2];
  const float* b1 = (const float*)d_in[3];
  const float* W2 = (const float*)d_in[4];
  const float* b2 = (const float*)d_in[5];
  const float* W3 = (const float*)d_in[6];
  const float* b3 = (const float*)d_in[7];
  float* outp = (float*)d_out;

  const int n  = in_sizes[0] / 64;   // 100000
  const int ne = in_sizes[1] / 2;    // 800000
  const int* srci = ei;
  const int* dsti = ei + ne;
  const int nbkt = (n + (1 << BKT_SH) - 1) >> BKT_SH;   // 391
  const int nseg = (ne + B1_EPB - 1) / B1_EPB;          // 196

  const size_t N64 = (size_t)n * 64;
  unsigned short* xb   = (unsigned short*)d_ws;   // N*64 bf16
  unsigned short* bufA = xb + N64;                // N*64 bf16 (h1)
  unsigned short* bufB = bufA + N64;              // N*64 bf16 (h2)
  uint2* ebuf   = (uint2*)(bufB + N64);           // E x (src,dst)
  int* row_off  = (int*)(ebuf + ne);              // N+1
  int* part     = row_off + n + 1;                // nseg*PSTRIDE
  int* bbase    = part + nseg * PSTRIDE;          // nbkt+1
  int* bcur     = bbase + nbkt + 1;               // nbkt
  int* ssrc     = bcur + nbkt;                    // E

  const int TB = 256;
  const int fus_blocks = 1568;                    // 1 tile/wave (6250 tiles)

  // ---- CSR build + x->bf16 (4 dispatches, no memset) ----
  bhist_cvt_k<<<784, TB, 0, stream>>>(dsti, part, ne, x, xb, (int)(N64 / 4), nbkt, nseg);
  bscan_k<<<1, 512, 0, stream>>>(part, bbase, bcur, nbkt, nseg, ne);
  bucket_k<<<nseg, TB, 0, stream>>>(srci, dsti, bcur, ebuf, ne, nbkt);
  fillb_k<<<nbkt, TB, 0, stream>>>(ebuf, bbase, row_off, ssrc, n, ne);

  // ---- fused layers ----
  fused_k<64, false><<<fus_blocks, TB, 0, stream>>>(xb,   row_off, ssrc, W1, b1, bufA, n);
  fused_k<64, false><<<fus_blocks, TB, 0, stream>>>(bufA, row_off, ssrc, W2, b2, bufB, n);
  fused_k<47, true ><<<fus_blocks, TB, 0, stream>>>(bufB, row_off, ssrc, W3, b3, outp, n);
}